// Round 2
// baseline (39.446 us; speedup 1.0000x reference)
//
#include <hip/hip_runtime.h>

// Antecedents: ant[i, r] = prod_j m_j[i, ri[r][j]], N=16384, n_sets=5^5,
// R = 3125, r = a*625 + b*125 + c*25 + d*5 + e (meshgrid 'ij').
// Pure streaming-write kernel: 204.8 MB out, 1.6 MB in.
//
// Round 1: 1 row/block + dword stores = 5.38 TB/s vs fill kernel's 6.8 TB/s.
// Round 2: 8 rows/block -> 100000 B contiguous 16B-aligned chunk per block,
// float4 stores, tail waste 6% -> 2.3%.

#define NSAMP 16384
#define NRULE 3125
#define ROWS_PER_BLOCK 8
#define CHUNK_ELEMS (ROWS_PER_BLOCK * NRULE)      // 25000 floats
#define CHUNK_VEC4 (CHUNK_ELEMS / 4)              // 6250 float4 (exact)

__global__ __launch_bounds__(256) void antecedents_kernel(
    const float* __restrict__ m0, const float* __restrict__ m1,
    const float* __restrict__ m2, const float* __restrict__ m3,
    const float* __restrict__ m4, float* __restrict__ out)
{
    __shared__ float p012[ROWS_PER_BLOCK][125];  // m0[a]*m1[b]*m2[c], idx a*25+b*5+c
    __shared__ float p34[ROWS_PER_BLOCK][25];    // m3[d]*m4[e],       idx d*5+e

    const unsigned t = threadIdx.x;
    const unsigned row0 = blockIdx.x * ROWS_PER_BLOCK;

    // Build partial-product tables for the block's 8 rows (1200 entries).
    for (unsigned u = t; u < ROWS_PER_BLOCK * 150u; u += 256u) {
        const unsigned rr = u / 150u;
        const unsigned k = u - rr * 150u;
        const unsigned row = row0 + rr;
        if (k < 125u) {
            const unsigned a = k / 25u;
            const unsigned b = (k / 5u) % 5u;
            const unsigned c = k % 5u;
            p012[rr][k] = m0[row * 5 + a] * m1[row * 5 + b] * m2[row * 5 + c];
        } else {
            const unsigned kk = k - 125u;
            p34[rr][kk] = m3[row * 5 + kk / 5u] * m4[row * 5 + kk % 5u];
        }
    }
    __syncthreads();

    // Block's output chunk: 25000 floats starting at a 16B-aligned address.
    float4* __restrict__ outv =
        (float4*)(out + (size_t)blockIdx.x * CHUNK_ELEMS);

    for (unsigned q = t; q < CHUNK_VEC4; q += 256u) {
        float4 v;
        unsigned fe = q * 4u;  // local flat element index
        float* vp = (float*)&v;
#pragma unroll
        for (int k = 0; k < 4; ++k) {
            const unsigned rr = fe / (unsigned)NRULE;       // local row (magic-mul)
            const unsigned r = fe - rr * (unsigned)NRULE;   // rule index
            const unsigned hi = r / 25u;                    // a*25+b*5+c
            const unsigned lo = r - hi * 25u;               // d*5+e
            vp[k] = p012[rr][hi] * p34[rr][lo];
            ++fe;
        }
        outv[q] = v;
    }
}

extern "C" void kernel_launch(void* const* d_in, const int* in_sizes, int n_in,
                              void* d_out, int out_size, void* d_ws, size_t ws_size,
                              hipStream_t stream) {
    const float* m0 = (const float*)d_in[0];
    const float* m1 = (const float*)d_in[1];
    const float* m2 = (const float*)d_in[2];
    const float* m3 = (const float*)d_in[3];
    const float* m4 = (const float*)d_in[4];
    float* out = (float*)d_out;

    antecedents_kernel<<<NSAMP / ROWS_PER_BLOCK, 256, 0, stream>>>(
        m0, m1, m2, m3, m4, out);
}